// Round 13
// baseline (267.038 us; speedup 1.0000x reference)
//
#include <hip/hip_runtime.h>

typedef __attribute__((ext_vector_type(8))) short short8;
typedef __attribute__((ext_vector_type(4))) float floatx4;
typedef __attribute__((ext_vector_type(2))) float floatx2;

#define LOG2E 1.44269504088896340736f

// raw barrier: drains LDS only; global loads stay in flight
#define BAR() asm volatile("s_waitcnt lgkmcnt(0)\n\ts_barrier" ::: "memory")

__device__ __forceinline__ floatx2 F2(float v) { return (floatx2){v, v}; }

__device__ __forceinline__ unsigned short f2bf(float f) {
  unsigned u = __float_as_uint(f);
  u += 0x7FFFu + ((u >> 16) & 1u);
  return (unsigned short)(u >> 16);
}

__device__ __forceinline__ unsigned cvtpk(float lo, float hi) {
  unsigned r;
  asm("v_cvt_pk_bf16_f32 %0, %1, %2" : "=v"(r) : "v"(lo), "v"(hi));
  return r;
}

// R13: 1024 threads = 16 waves = 4 waves/SIMD on one CU (m69: <=128 VGPR
// fits 16 waves/CU). Each wave owns 16 cols -> weight set halves to 48 VGPR
// (R5 proved this footprint co-resides at 45% occupancy). 4 waves/SIMD
// interleave the read->MFMA->proc->write phases that R12's 2 waves serialized.
__global__ __launch_bounds__(1024, 1) void tlstm_kernel(
    const float* __restrict__ x, const float* __restrict__ tim,
    const float* __restrict__ Wi, const float* __restrict__ bi,
    const float* __restrict__ Wh, const float* __restrict__ bh,
    float* __restrict__ out)
{
  // state: 16 rows [h0,c0,...,h7,c7] x 256 k, row stride 272 ushorts, dbuf.
  // Read 16B-slot spread 2-way (free); write twist pos=col^(((row>>2)&3)<<3)
  // cancels against the read base XOR (R12-verified layout).
  __shared__ __align__(16) unsigned short Sst[2 * 4352];   // 17 KB
  __shared__ __align__(16) unsigned short Sx[2 * 2176];    //  8.5 KB
  __shared__ __align__(16) float WMt[2048];                // [t][8 batches]

  const int tid = threadIdx.x;
  const int wv  = tid >> 6;        // wave 0..15, owns cols [wv*16, wv*16+16)
  const int l   = tid & 63;
  const int q   = l >> 4;
  const int r   = l & 15;
  const int b0  = blockIdx.x * 8;  // 8 batches per block, 256 blocks

  const int col = wv * 16 + r;

  // ---- weights for this wave's single 16-col tile (B-operand layout) ----
  short8 wh[8];                    // 32 VGPR
#pragma unroll
  for (int c = 0; c < 8; ++c)
#pragma unroll
    for (int j = 0; j < 8; ++j)
      wh[c][j] = (short)f2bf(Wh[(c * 32 + q * 8 + j) * 256 + col]);
  short8 wi[4];                    // 16 VGPR
#pragma unroll
  for (int c = 0; c < 4; ++c)
#pragma unroll
    for (int j = 0; j < 8; ++j)
      wi[c][j] = (short)f2bf(Wi[(c * 32 + q * 8 + j) * 256 + col]);
  const float bhc = bh[col], bic = bi[col];

  // ---- loop-invariant addresses (ushort units) ----
  const int raS = r * 272 + ((q * 8) ^ (((r >> 2) & 3) << 3));
  const int raX = r * 136 + q * 8;
  const int iA  = (4 * q) * 272 + (col ^ (q << 3));   // h-row batch 2q @ col
  // x staging: wave wv stages row wv (batch wv>>1, parity wv&1), 2 floats/lane
  const int xw  = wv * 136 + 2 * l;
  const float* xbase = x + (long)(b0 + (wv >> 1)) * 32768 + (wv & 1) * 128 + 2 * l;

  // ---- one-time init ----
  {
    unsigned* S32 = (unsigned*)Sst;
    for (int i = tid; i < 2176; i += 1024) S32[i] = 0;   // zero state buf0
  }
  for (int i = tid; i < 2040; i += 1024) {
    int t = i >> 3, bl = i & 7;
    float t0 = tim[(b0 + bl) * 256 + t];
    float t1 = tim[(b0 + bl) * 256 + t + 1];
    WMt[i] = 1.f - 1.f / logf(t1 - t0 + 2.7193f);
  }
  {  // stage pair 0 into Sx buf0
    floatx2 v = *(const floatx2*)xbase;
    *(unsigned*)&Sx[xw] = cvtpk(v.x, v.y);
  }
  __syncthreads();

  // lane state, batch-packed: .x = batch 2q, .y = batch 2q+1 at this col
  floatx2 cS = F2(0.f), hS = F2(0.f), gS = F2(0.f);
  int xro = 0;

  // packed gate math: 4 exp2 + 2 rcp per call (combined reciprocal)
  auto proc2 = [&](floatx2 zin, floatx2 cpin, floatx2 wm, int woff) {
    floatx2 z  = __builtin_elementwise_min(__builtin_elementwise_max(zin,  F2(-10.f)), F2(10.f));
    floatx2 cp = __builtin_elementwise_min(__builtin_elementwise_max(cpin, F2(-10.f)), F2(10.f));
    floatx2 mz = z * F2(-LOG2E);
    floatx2 u  = {__builtin_amdgcn_exp2f(mz.x), __builtin_amdgcn_exp2f(mz.y)};
    floatx2 u2 = u * u;
    floatx2 mc = cp * F2(-2.f * LOG2E);
    floatx2 v  = {__builtin_amdgcn_exp2f(mc.x), __builtin_amdgcn_exp2f(mc.y)};
    floatx2 a1 = u + F2(1.f), a2 = u2 + F2(1.f), a3 = v + F2(1.f);
    floatx2 p12 = a1 * a2;
    floatx2 pr  = p12 * a3;
    floatx2 D   = {__builtin_amdgcn_rcpf(pr.x), __builtin_amdgcn_rcpf(pr.y)};
    floatx2 Da3 = D * a3;
    floatx2 g   = Da3 * a2;                 // sigmoid(z)
    floatx2 ir2 = Da3 * a1;                 // 1/(1+u2)
    floatx2 ir3 = D * p12;                  // 1/(1+v)
    floatx2 Cb  = ir2 - u2 * ir2;           // tanh(z)
    floatx2 Cs  = ir3 - v * ir3;            // tanh(cp)
    floatx2 Cst = cS - Cs * wm;             // c - Cs*(1-wt)
    floatx2 cn  = g * (Cst + Cb);
    floatx2 s   = Cb * Cb;                  // tanh(Cb) Taylor-13
    floatx2 P   = F2(0.003592028f);
    P = P * s + F2(-0.008863236f);
    P = P * s + F2(0.021869488f);
    P = P * s + F2(-0.053968254f);
    P = P * s + F2(0.133333333f);
    P = P * s + F2(-0.333333333f);
    P = P * s + F2(1.0f);
    floatx2 hn = g * (Cb * P);
    unsigned pk0 = cvtpk(hn.x, cn.x);       // batch 2q:   lo=h, hi=c
    unsigned pk1 = cvtpk(hn.y, cn.y);       // batch 2q+1
    Sst[woff + iA]       = (unsigned short)pk0;
    Sst[woff + iA + 272] = (unsigned short)(pk0 >> 16);
    Sst[woff + iA + 544] = (unsigned short)pk1;
    Sst[woff + iA + 816] = (unsigned short)(pk1 >> 16);
    cS = cn; gS = g; hS = hn;
  };

  floatx4 xs;  // x-proj (+bi): [b2q parA, b2q parB, b2q+1 parA, b2q+1 parB]
  auto loadx = [&]() {
    short8 xf[4];
#pragma unroll
    for (int c = 0; c < 4; ++c)
      xf[c] = *(const short8*)&Sx[xro + raX + 32 * c];
    floatx4 a = {bic, bic, bic, bic};
#pragma unroll
    for (int c = 0; c < 4; ++c)
      a = __builtin_amdgcn_mfma_f32_16x16x32_bf16(xf[c], wi[c], a, 0, 0, 0);
    xs = a;
  };

  auto dostep = [&](int roff, int woff, int par, int wmoff) {
    short8 sf[8];
#pragma unroll
    for (int c = 0; c < 8; ++c)
      sf[c] = *(const short8*)&Sst[roff + raS + 32 * c];
    // 2 independent 4-deep chains
    floatx4 ae = {bhc, bhc, bhc, bhc};
    floatx4 ao = {0.f, 0.f, 0.f, 0.f};
#pragma unroll
    for (int c = 0; c < 8; c += 2) {
      ae = __builtin_amdgcn_mfma_f32_16x16x32_bf16(sf[c],     wh[c],     ae, 0, 0, 0);
      ao = __builtin_amdgcn_mfma_f32_16x16x32_bf16(sf[c + 1], wh[c + 1], ao, 0, 0, 0);
    }
    floatx4 A = ae + ao;
    floatx2 wm = *(const floatx2*)&WMt[wmoff + 2 * q];
    floatx2 z  = {A[0] + xs[par], A[2] + xs[2 + par]};
    floatx2 cp = {A[1],           A[3]};
    proc2(z, cp, wm, woff);
    BAR();
  };

  for (int p = 0; p < 127; ++p) {
    floatx2 nv = *(const floatx2*)(xbase + (p + 1) * 256);  // next pair's x
    loadx();
    // step A (t = 2p): read buf0, write buf1
    dostep(0, 4352, 0, 16 * p);
    // finish staging next pair into the other x buffer
    *(unsigned*)&Sx[(xro ^ 2176) + xw] = cvtpk(nv.x, nv.y);
    // step B (t = 2p+1): read buf1, write buf0
    dostep(4352, 0, 1, 16 * p + 8);
    xro ^= 2176;
  }

  // tail: t = 254 (step A of pair 127; staged at p=126)
  loadx();
  dostep(0, 4352, 0, 16 * 127);

  // ---- epilogue: res = g_last @ Wh + bh; g-tile into buf0 ----
  Sst[iA]       = f2bf(gS.x);  Sst[iA + 272] = 0;
  Sst[iA + 544] = f2bf(gS.y);  Sst[iA + 816] = 0;
  BAR();
  short8 gf[8];
#pragma unroll
  for (int c = 0; c < 8; ++c)
    gf[c] = *(const short8*)&Sst[raS + 32 * c];
  floatx4 res = {bhc, bhc, bhc, bhc};
#pragma unroll
  for (int c = 0; c < 8; ++c)
    res = __builtin_amdgcn_mfma_f32_16x16x32_bf16(gf[c], wh[c], res, 0, 0, 0);

  const long P  = 2048L * 256;
  const long o0 = (long)(b0 + 2 * q) * 256;
  const long o1 = o0 + 256;
  out[o0 + col]         = res[0];
  out[o1 + col]         = res[2];
  out[P + o0 + col]     = hS.x;
  out[P + o1 + col]     = hS.y;
  out[2 * P + o0 + col] = cS.x;
  out[2 * P + o1 + col] = cS.y;
}

extern "C" void kernel_launch(void* const* d_in, const int* in_sizes, int n_in,
                              void* d_out, int out_size, void* d_ws, size_t ws_size,
                              hipStream_t stream) {
  const float* xin = (const float*)d_in[0];
  const float* tim = (const float*)d_in[1];
  const float* Wi  = (const float*)d_in[2];
  const float* bi  = (const float*)d_in[3];
  const float* Wh  = (const float*)d_in[4];
  const float* bh  = (const float*)d_in[5];
  tlstm_kernel<<<dim3(256), dim3(1024), 0, stream>>>(xin, tim, Wi, bi, Wh, bh, (float*)d_out);
}

// Round 14
// 238.653 us; speedup vs baseline: 1.1189x; 1.1189x over previous
//
#include <hip/hip_runtime.h>

typedef __attribute__((ext_vector_type(8))) short short8;
typedef __attribute__((ext_vector_type(4))) float floatx4;
typedef __attribute__((ext_vector_type(2))) float floatx2;
typedef __attribute__((ext_vector_type(2))) unsigned uintx2;

#define NLOG2E -1.44269504088896340736f   // weight pre-scale: z_s = -log2e * z
#define NLN2   -0.69314718055994530942f   // epilogue unscale: 1/NLOG2E
#define CLMP    14.4269504089f            // 10*log2e: clamp z_true >= -10 (scaled: min)

// raw barrier: drains LDS only; global loads stay in flight
#define BAR() asm volatile("s_waitcnt lgkmcnt(0)\n\ts_barrier" ::: "memory")

__device__ __forceinline__ floatx2 F2(float v) { return (floatx2){v, v}; }

__device__ __forceinline__ unsigned short f2bf(float f) {
  unsigned u = __float_as_uint(f);
  u += 0x7FFFu + ((u >> 16) & 1u);
  return (unsigned short)(u >> 16);
}

__device__ __forceinline__ unsigned cvtpk(float lo, float hi) {
  unsigned r;
  asm("v_cvt_pk_bf16_f32 %0, %1, %2" : "=v"(r) : "v"(lo), "v"(hi));
  return r;
}

// 1 block/CU (grid=256): 256-VGPR cap, weights can never spill (R6 lesson).
// R12-verified LDS layout: row stride 272 ushorts -> 2-way read slots (free);
// write twist pos=col^(((row>>2)&3)<<3) cancels on the read base XOR.
__global__ __launch_bounds__(512, 1) void tlstm_kernel(
    const float* __restrict__ x, const float* __restrict__ tim,
    const float* __restrict__ Wi, const float* __restrict__ bi,
    const float* __restrict__ Wh, const float* __restrict__ bh,
    float* __restrict__ out)
{
  __shared__ __align__(16) unsigned short Sst[2 * 4352];   // 17 KB state dbuf
  __shared__ __align__(16) unsigned short Sx[2 * 2176];    //  8.5 KB x dbuf
  __shared__ __align__(16) float WMt[2048];                // [t][8 batches]

  const int tid = threadIdx.x;
  const int wv  = tid >> 6;        // wave 0..7, owns cols [wv*32, wv*32+32)
  const int l   = tid & 63;
  const int q   = l >> 4;
  const int r   = l & 15;
  const int b0  = blockIdx.x * 8;  // 8 batches per block, 256 blocks

  const int col1 = wv * 32 + r;
  const int col2 = col1 + 16;

  // ---- weights pre-scaled by -log2e (B-operand layout, both 16-col tiles) ----
  short8 wh[2][8];
#pragma unroll
  for (int tx = 0; tx < 2; ++tx)
#pragma unroll
    for (int c = 0; c < 8; ++c)
#pragma unroll
      for (int j = 0; j < 8; ++j)
        wh[tx][c][j] = (short)f2bf(NLOG2E * Wh[(c * 32 + q * 8 + j) * 256 + wv * 32 + tx * 16 + r]);
  short8 wi[2][4];
#pragma unroll
  for (int tx = 0; tx < 2; ++tx)
#pragma unroll
    for (int c = 0; c < 4; ++c)
#pragma unroll
      for (int j = 0; j < 8; ++j)
        wi[tx][c][j] = (short)f2bf(NLOG2E * Wi[(c * 32 + q * 8 + j) * 256 + wv * 32 + tx * 16 + r]);
  const float bh1 = NLOG2E * bh[col1], bh2 = NLOG2E * bh[col2];
  const float bi1 = NLOG2E * bi[col1], bi2 = NLOG2E * bi[col2];

  // ---- loop-invariant addresses (ushort units) ----
  const int raS = r * 272 + ((q * 8) ^ (((r >> 2) & 3) << 3));
  const int raX = r * 136 + q * 8;
  const int iA1 = (4 * q) * 272 + (col1 ^ (q << 3));
  const int iA2 = (4 * q) * 272 + (col2 ^ (q << 3));
  const int xw  = (2 * wv + (l >> 5)) * 136 + 4 * (l & 31);
  const float* xbase = x + (long)(b0 + wv) * 32768 + (l >> 5) * 128 + 4 * (l & 31);

  // ---- one-time init ----
  {
    unsigned* S32 = (unsigned*)Sst;
    for (int i = tid; i < 2176; i += 512) S32[i] = 0;   // zero state buf0
  }
  for (int i = tid; i < 2040; i += 512) {
    int t = i >> 3, bl = i & 7;
    float t0 = tim[(b0 + bl) * 256 + t];
    float t1 = tim[(b0 + bl) * 256 + t + 1];
    WMt[i] = 1.f - 1.f / logf(t1 - t0 + 2.7193f);
  }
  {  // stage pair 0 into Sx buf0
    floatx4 v = *(const floatx4*)xbase;
    uintx2 pk = {cvtpk(v.x, v.y), cvtpk(v.z, v.w)};
    *(uintx2*)&Sx[xw] = pk;
  }
  __syncthreads();

  // lane state as (col1,col2) pairs: P0 = batch 2q, P1 = batch 2q+1 (true scale)
  floatx2 cP0 = F2(0.f), cP1 = F2(0.f);
  floatx2 hP0 = F2(0.f), hP1 = F2(0.f);
  floatx2 gP0 = F2(0.f), gP1 = F2(0.f);

  // packed gate math, scaled domain: 4 exp2 + 2 rcp; one-sided clamps
  auto proc2 = [&](floatx2 zin, floatx2 cpin, floatx2& cio, floatx2& gio,
                   floatx2& hio, float wmv, int ih0, int ih1, int woff) {
    floatx2 z  = __builtin_elementwise_min(zin,  F2(CLMP));  // z_true >= -10
    floatx2 cp = __builtin_elementwise_min(cpin, F2(CLMP));
    floatx2 u  = {__builtin_amdgcn_exp2f(z.x), __builtin_amdgcn_exp2f(z.y)};   // e^{-z}
    floatx2 u2 = u * u;
    floatx2 c2 = cp + cp;
    floatx2 v  = {__builtin_amdgcn_exp2f(c2.x), __builtin_amdgcn_exp2f(c2.y)}; // e^{-2cp}
    floatx2 a1 = u + F2(1.f), a2 = u2 + F2(1.f), a3 = v + F2(1.f);
    floatx2 p12 = a1 * a2;
    floatx2 pr  = p12 * a3;
    floatx2 D   = {__builtin_amdgcn_rcpf(pr.x), __builtin_amdgcn_rcpf(pr.y)};
    floatx2 Da3 = D * a3;
    floatx2 g   = Da3 * a2;                 // sigmoid(z_true)
    floatx2 ir2 = Da3 * a1;                 // 1/(1+u2)
    floatx2 ir3 = D * p12;                  // 1/(1+v)
    floatx2 Cb  = ir2 - u2 * ir2;           // tanh(z_true)
    floatx2 Cs  = ir3 - v * ir3;            // tanh(cp_true)
    floatx2 Cst = cio - Cs * F2(wmv);       // c - Cs*(1-wt)
    floatx2 cn  = g * (Cst + Cb);
    floatx2 s   = Cb * Cb;                  // tanh(Cb), Taylor-11 (err<=2.6e-3)
    floatx2 P   = F2(-0.008863236f);
    P = P * s + F2(0.021869488f);
    P = P * s + F2(-0.053968254f);
    P = P * s + F2(0.133333333f);
    P = P * s + F2(-0.333333333f);
    P = P * s + F2(1.0f);
    floatx2 hn = g * (Cb * P);
    unsigned pk0 = cvtpk(hn.x, cn.x);       // col1: lo=h, hi=c
    unsigned pk1 = cvtpk(hn.y, cn.y);       // col2
    Sst[woff + ih0]       = (unsigned short)pk0;
    Sst[woff + ih0 + 272] = (unsigned short)(pk0 >> 16);
    Sst[woff + ih1]       = (unsigned short)pk1;
    Sst[woff + ih1 + 272] = (unsigned short)(pk1 >> 16);
    cio = cn; gio = g; hio = hn;
  };

  floatx4 xa1, xa2;  // x-proj (+bi_s): [b2q parA, b2q parB, b2q+1 parA, b2q+1 parB]
  auto loadx = [&](int xoff) {
    short8 xf[4];
#pragma unroll
    for (int c = 0; c < 4; ++c)
      xf[c] = *(const short8*)&Sx[xoff + raX + 32 * c];
    floatx4 x1 = {bi1, bi1, bi1, bi1};
    floatx4 x2 = {bi2, bi2, bi2, bi2};
#pragma unroll
    for (int c = 0; c < 4; ++c) {
      x1 = __builtin_amdgcn_mfma_f32_16x16x32_bf16(xf[c], wi[0][c], x1, 0, 0, 0);
      x2 = __builtin_amdgcn_mfma_f32_16x16x32_bf16(xf[c], wi[1][c], x2, 0, 0, 0);
    }
    xa1 = x1; xa2 = x2;
  };

  auto dostep = [&](int roff, int woff, int par, int wmoff) {
    short8 sf[8];
#pragma unroll
    for (int c = 0; c < 8; ++c)
      sf[c] = *(const short8*)&Sst[roff + raS + 32 * c];
    // single chain per tile (sum-bound, not latency-bound: drop the merge adds)
    floatx4 a1 = {bh1, bh1, bh1, bh1};
#pragma unroll
    for (int c = 0; c < 8; ++c)
      a1 = __builtin_amdgcn_mfma_f32_16x16x32_bf16(sf[c], wh[0][c], a1, 0, 0, 0);
    floatx4 a2 = {bh2, bh2, bh2, bh2};
#pragma unroll
    for (int c = 0; c < 8; ++c)
      a2 = __builtin_amdgcn_mfma_f32_16x16x32_bf16(sf[c], wh[1][c], a2, 0, 0, 0);
    floatx2 wm = *(const floatx2*)&WMt[wmoff];
    floatx2 z0  = {a1[0] + xa1[par],     a2[0] + xa2[par]};
    floatx2 cp0 = {a1[1],                a2[1]};
    floatx2 z1  = {a1[2] + xa1[2 + par], a2[2] + xa2[2 + par]};
    floatx2 cp1 = {a1[3],                a2[3]};
    proc2(z0, cp0, cP0, gP0, hP0, wm.x, iA1,       iA2,       woff);
    proc2(z1, cp1, cP1, gP1, hP1, wm.y, iA1 + 544, iA2 + 544, woff);
    BAR();
  };

  auto stage = [&](floatx4 nv, int xoff) {
    uintx2 pk = {cvtpk(nv.x, nv.y), cvtpk(nv.z, nv.w)};
    *(uintx2*)&Sx[xoff + xw] = pk;
  };

  // 2-pair unroll: Sx offsets become literals (pair parity fixed per slot)
  for (int p = 0; p < 126; p += 2) {
    {  // pair p (x in buf0), stages pair p+1 -> buf1
      floatx4 nv = *(const floatx4*)(xbase + (long)(p + 1) * 256);
      loadx(0);
      dostep(0, 4352, 0, 16 * p + 2 * q);
      stage(nv, 2176);
      dostep(4352, 0, 1, 16 * p + 8 + 2 * q);
    }
    {  // pair p+1 (x in buf1), stages pair p+2 -> buf0
      floatx4 nv = *(const floatx4*)(xbase + (long)(p + 2) * 256);
      loadx(2176);
      dostep(0, 4352, 0, 16 * (p + 1) + 2 * q);
      stage(nv, 0);
      dostep(4352, 0, 1, 16 * (p + 1) + 8 + 2 * q);
    }
  }
  {  // pair 126 (x in buf0), stages pair 127 -> buf1
    floatx4 nv = *(const floatx4*)(xbase + (long)127 * 256);
    loadx(0);
    dostep(0, 4352, 0, 16 * 126 + 2 * q);
    stage(nv, 2176);
    dostep(4352, 0, 1, 16 * 126 + 8 + 2 * q);
  }
  // tail: t = 254 (step A of pair 127, x in buf1)
  loadx(2176);
  dostep(0, 4352, 0, 16 * 127 + 2 * q);

  // ---- epilogue: res = -ln2 * (g_last @ Wh_s + bh_s); g-tile into buf0 ----
  Sst[iA1]       = f2bf(gP0.x);  Sst[iA1 + 272] = 0;
  Sst[iA1 + 544] = f2bf(gP1.x);  Sst[iA1 + 816] = 0;
  Sst[iA2]       = f2bf(gP0.y);  Sst[iA2 + 272] = 0;
  Sst[iA2 + 544] = f2bf(gP1.y);  Sst[iA2 + 816] = 0;
  BAR();
  short8 gf[8];
#pragma unroll
  for (int c = 0; c < 8; ++c)
    gf[c] = *(const short8*)&Sst[raS + 32 * c];
  floatx4 r1 = {bh1, bh1, bh1, bh1};
  floatx4 r2 = {bh2, bh2, bh2, bh2};
#pragma unroll
  for (int c = 0; c < 8; ++c) {
    r1 = __builtin_amdgcn_mfma_f32_16x16x32_bf16(gf[c], wh[0][c], r1, 0, 0, 0);
    r2 = __builtin_amdgcn_mfma_f32_16x16x32_bf16(gf[c], wh[1][c], r2, 0, 0, 0);
  }

  const long P  = 2048L * 256;
  const long o0 = (long)(b0 + 2 * q) * 256;
  const long o1 = o0 + 256;
  out[o0 + col1]         = NLN2 * r1[0];
  out[o1 + col1]         = NLN2 * r1[2];
  out[o0 + col2]         = NLN2 * r2[0];
  out[o1 + col2]         = NLN2 * r2[2];
  out[P + o0 + col1]     = hP0.x;
  out[P + o1 + col1]     = hP1.x;
  out[P + o0 + col2]     = hP0.y;
  out[P + o1 + col2]     = hP1.y;
  out[2 * P + o0 + col1] = cP0.x;
  out[2 * P + o1 + col1] = cP1.x;
  out[2 * P + o0 + col2] = cP0.y;
  out[2 * P + o1 + col2] = cP1.y;
}

extern "C" void kernel_launch(void* const* d_in, const int* in_sizes, int n_in,
                              void* d_out, int out_size, void* d_ws, size_t ws_size,
                              hipStream_t stream) {
  const float* xin = (const float*)d_in[0];
  const float* tim = (const float*)d_in[1];
  const float* Wi  = (const float*)d_in[2];
  const float* bi  = (const float*)d_in[3];
  const float* Wh  = (const float*)d_in[4];
  const float* bh  = (const float*)d_in[5];
  tlstm_kernel<<<dim3(256), dim3(512), 0, stream>>>(xin, tim, Wi, bi, Wh, bh, (float*)d_out);
}